// Round 10
// baseline (629.352 us; speedup 1.0000x reference)
//
#include <hip/hip_runtime.h>

#define NN 100000
#define NE 1600000

constexpr int NBUC = 196;       // bucket = dst >> 9 (512 nodes/bucket)
constexpr int BIN_CHUNK = 4096;
constexpr int NB_BIN = (NE + BIN_CHUNK - 1) / BIN_CHUNK;  // 391
constexpr int BN_BLOCKS = 1024; // bn_stats grid (grid-stride)

typedef __attribute__((ext_vector_type(8))) short s16x8;
typedef __attribute__((ext_vector_type(4))) float f32x4;
typedef __attribute__((ext_vector_type(2))) float f32x2;

template <int M>
struct IC {
    static constexpr int value = M;
};

__device__ inline unsigned short f2bf(float f) {  // RNE fp32 -> bf16 bits
    unsigned int u = __float_as_uint(f);
    return (unsigned short)((u + 0x7fffu + ((u >> 16) & 1u)) >> 16);
}
__device__ inline float bf_lo(unsigned int pk) { return __uint_as_float(pk << 16); }
__device__ inline float bf_hi(unsigned int pk) { return __uint_as_float(pk & 0xffff0000u); }
__device__ inline float h2f(unsigned int u) {  // low 16 bits = fp16
    _Float16 h;
    unsigned short s = (unsigned short)u;
    __builtin_memcpy(&h, &s, 2);
    return (float)h;
}

__global__ void zero_u32(unsigned int* p, int n) {
    int i = blockIdx.x * blockDim.x + threadIdx.x;
    if (i < n) p[i] = 0u;
}

// Histogram of dst buckets (LDS-combined, 196 global atomics per block).
__global__ __launch_bounds__(256) void bucket_count(const int* __restrict__ dst,
                                                    int* __restrict__ bcount) {
    __shared__ int hist[NBUC];
    int t = threadIdx.x;
    for (int b = t; b < NBUC; b += 256) hist[b] = 0;
    __syncthreads();
    int beg = blockIdx.x * BIN_CHUNK;
    int end = min(beg + BIN_CHUNK, NE);
    for (int i = beg + t; i < end; i += 256) atomicAdd(&hist[dst[i] >> 9], 1);
    __syncthreads();
    for (int b = t; b < NBUC; b += 256)
        if (hist[b]) atomicAdd(&bcount[b], hist[b]);
}

// Serial 196-entry exclusive scan; writes bucket bases + bin cursors.
__global__ void bucket_scan(const int* __restrict__ bcount, int* __restrict__ bbase,
                            int* __restrict__ bucket_cursor, int* __restrict__ offsets) {
    if (threadIdx.x == 0) {
        int run = 0;
        for (int b = 0; b < NBUC; ++b) {
            bbase[b] = run;
            bucket_cursor[b] = run;
            run += bcount[b];
        }
        bbase[NBUC] = NE;
        offsets[NN] = NE;
    }
}

// Bucket-major packed intermediate: (local_dst9 << 17) | src17. Per-block LDS
// histogram, per-bucket chunk reservation, contiguous 4B writes.
__global__ __launch_bounds__(256) void bin_edges(const int* __restrict__ src,
                                                 const int* __restrict__ dst,
                                                 int* __restrict__ bucket_cursor,
                                                 unsigned int* __restrict__ binned) {
    __shared__ int hist[NBUC];
    __shared__ int base[NBUC];
    int t = threadIdx.x;
    for (int b = t; b < NBUC; b += 256) hist[b] = 0;
    __syncthreads();
    int beg = blockIdx.x * BIN_CHUNK;
    int end = min(beg + BIN_CHUNK, NE);
    for (int i = beg + t; i < end; i += 256) atomicAdd(&hist[dst[i] >> 9], 1);
    __syncthreads();
    for (int b = t; b < NBUC; b += 256) {
        base[b] = hist[b] ? atomicAdd(&bucket_cursor[b], hist[b]) : 0;
        hist[b] = 0;
    }
    __syncthreads();
    for (int i = beg + t; i < end; i += 256) {
        int d = dst[i];
        int bk = d >> 9;
        int loc = atomicAdd(&hist[bk], 1);
        binned[base[bk] + loc] = ((unsigned)(d & 511) << 17) | (unsigned)src[i];
    }
}

// One block per bucket: LDS counting sort over the bucket's 512 nodes.
// Emits offsets + csr_src/csr_dst with sequential (in-bucket) global writes.
__global__ __launch_bounds__(256) void bucket_sort(const unsigned int* __restrict__ binned,
                                                   const int* __restrict__ bbase,
                                                   int* __restrict__ offsets,
                                                   int* __restrict__ csr_src,
                                                   int* __restrict__ csr_dst) {
    __shared__ int deg[512];
    __shared__ int loc[512];
    __shared__ int s2[256];
    int t = threadIdx.x;
    int b = blockIdx.x;
    int beg = bbase[b], end = bbase[b + 1];
    int nbase = b << 9;
    deg[t] = 0;
    deg[t + 256] = 0;
    __syncthreads();
    for (int i = beg + t; i < end; i += 256) atomicAdd(&deg[binned[i] >> 17], 1);
    __syncthreads();
    int pairsum = deg[2 * t] + deg[2 * t + 1];
    s2[t] = pairsum;
    __syncthreads();
    for (int off = 1; off < 256; off <<= 1) {
        int v = (t >= off) ? s2[t - off] : 0;
        __syncthreads();
        s2[t] += v;
        __syncthreads();
    }
    int ex = s2[t] - pairsum;  // exclusive pair base
    loc[2 * t] = ex;
    loc[2 * t + 1] = ex + deg[2 * t];
    __syncthreads();
    for (int i = t; i < 512; i += 256) {
        int node = nbase + i;
        if (node < NN) offsets[node] = beg + loc[i];
    }
    __syncthreads();
    for (int i = beg + t; i < end; i += 256) {
        unsigned int v = binned[i];
        int dl = v >> 17;
        int pos = atomicAdd(&loc[dl], 1);
        csr_src[beg + pos] = (int)(v & 0x1FFFFu);
        csr_dst[beg + pos] = nbase + dl;
    }
}

// Transpose + fp32->bf16 all weights once per launch, and FOLD the attention
// score vectors into the GEMM B matrix: scores are linear in X, so
// e_src[n,h] = X @ (W[:,h*64:]*as[h]) -> 4 extra B columns (128..131) per
// tile: [was_h0, was_h1, wad_h0, wad_h1].
// Wtcat: 2 tiles x 132 cols x 128 k. tile0 = W0(h)+scores; tile1 = skip|proj.
// Wt1/Wt2: 132 cols x 64 k.
__global__ void prep_weights(const float* __restrict__ W0, const float* __restrict__ skip0,
                             const float* __restrict__ projW, const float* __restrict__ W1,
                             const float* __restrict__ W2,
                             const float* __restrict__ as0, const float* __restrict__ ad0,
                             const float* __restrict__ as1, const float* __restrict__ ad1,
                             const float* __restrict__ as2, const float* __restrict__ ad2,
                             unsigned short* __restrict__ Wtcat,
                             unsigned short* __restrict__ Wt1,
                             unsigned short* __restrict__ Wt2) {
    int i = blockIdx.x * 256 + threadIdx.x;
    if (i < 16384) {  // Wtcat tile0 h cols
        int oc = i >> 7, k = i & 127;
        Wtcat[oc * 128 + k] = f2bf(W0[k * 128 + oc]);
    } else if (i < 32768) {  // Wtcat tile1: skip | proj
        int j = i - 16384;
        int oc = j >> 7, k = j & 127;
        float v = (oc < 64) ? skip0[k * 64 + oc] : projW[k * 64 + (oc - 64)];
        Wtcat[132 * 128 + oc * 128 + k] = f2bf(v);
    } else if (i < 40960) {  // Wt1 h cols
        int j = i - 32768, oc = j >> 6, k = j & 63;
        Wt1[oc * 64 + k] = f2bf(W1[k * 128 + oc]);
    } else if (i < 49152) {  // Wt2 h cols
        int j = i - 40960, oc = j >> 6, k = j & 63;
        Wt2[oc * 64 + k] = f2bf(W2[k * 128 + oc]);
    } else if (i < 50688) {  // score columns
        int e = i - 49152;
        if (e < 512) {  // Wtcat tile0 scores: 4 cols x 128 k
            int k = e >> 2, sc = e & 3, head = sc & 1;
            const float* av = (sc < 2 ? as0 : ad0) + head * 64;
            const float* wr = W0 + k * 128 + head * 64;
            float s = 0.f;
            for (int c = 0; c < 64; ++c) s += wr[c] * av[c];
            Wtcat[(128 + sc) * 128 + k] = f2bf(s);
        } else if (e < 1024) {  // tile1 score cols = 0 (unused)
            int j = e - 512, k = j >> 2, sc = j & 3;
            Wtcat[132 * 128 + (128 + sc) * 128 + k] = 0;
        } else if (e < 1280) {
            int j = e - 1024, k = j >> 2, sc = j & 3, head = sc & 1;
            const float* av = (sc < 2 ? as1 : ad1) + head * 64;
            const float* wr = W1 + k * 128 + head * 64;
            float s = 0.f;
            for (int c = 0; c < 64; ++c) s += wr[c] * av[c];
            Wt1[(128 + sc) * 64 + k] = f2bf(s);
        } else {
            int j = e - 1280, k = j >> 2, sc = j & 3, head = sc & 1;
            const float* av = (sc < 2 ? as2 : ad2) + head * 64;
            const float* wr = W2 + k * 128 + head * 64;
            float s = 0.f;
            for (int c = 0; c < 64; ++c) s += wr[c] * av[c];
            Wt2[(128 + sc) * 64 + k] = f2bf(s);
        }
    }
}

// MFMA bf16 GEMM: block = 64 rows x 132 cols (128 data + 4 score), 4 waves.
// A-side: NO LDS staging -- each lane loads its MFMA fragment slice directly
// from global (fp32 x for L0, fp16 hraw+BN+lrelu for L1/L2), converts to bf16
// in registers, and reuses it across all 9 column tiles. Only B lives in LDS
// (35.9KB for K=128 -> 4 blocks/CU vs 2 with A staged; 19KB for K=64).
// h written as [node][32] dwords of packed fp8-e4m3 (head0,head1) pairs.
// Scores via a 9th MFMA against cols 128+(lr&3) -> 1-shfl epilogue.
template <int K, bool L0, bool XFORM>
__global__ __launch_bounds__(256, 4) void gemm_mfma(
    const void* __restrict__ Xv, const unsigned short* __restrict__ Wt,
    unsigned int* __restrict__ Hq32, _Float16* __restrict__ skipx,
    _Float16* __restrict__ jkproj, const float* __restrict__ projb,
    const float* __restrict__ bnsc,
    unsigned int* __restrict__ e_srcpk, unsigned int* __restrict__ e_dstpk) {
    constexpr int KP = K + 8;
    constexpr int NC = 132;
    __shared__ unsigned short Bs[NC * KP];
    int t = threadIdx.x;
    int tile = L0 ? blockIdx.x : 0;
    int rbase = (L0 ? blockIdx.y : blockIdx.x) * 64;
    const unsigned short* Wtg = Wt + (size_t)tile * NC * K;

    for (int i = t; i < NC * (K / 8); i += 256) {
        int oc = i / (K / 8);
        int k8 = (i % (K / 8)) * 8;
        uint4 v = *(const uint4*)&Wtg[(size_t)oc * K + k8];
        *(uint4*)&Bs[oc * KP + k8] = v;
    }

    int lane = t & 63, wv = t >> 6;
    int lr = lane & 15, quad = lane >> 4;
    int arow = wv * 16 + lr;
    int grow = rbase + arow;
    bool rowok = grow < NN;

    // A fragments: K/32 x s16x8, loaded global->reg with inline bf16 convert.
    s16x8 afrag[K / 32];
#pragma unroll
    for (int ks = 0; ks < K / 32; ++ks) {
        int kq = ks * 32 + quad * 8;
        float v[8];
        if (rowok) {
            if constexpr (!XFORM) {
                const float* Xf = (const float*)Xv;
                float4 p0 = *(const float4*)&Xf[(size_t)grow * K + kq];
                float4 p1 = *(const float4*)&Xf[(size_t)grow * K + kq + 4];
                v[0] = p0.x; v[1] = p0.y; v[2] = p0.z; v[3] = p0.w;
                v[4] = p1.x; v[5] = p1.y; v[6] = p1.z; v[7] = p1.w;
            } else {
                const _Float16* Xh = (const _Float16*)Xv;
                uint4 rw = *(const uint4*)&Xh[(size_t)grow * K + kq];
                unsigned rr[4] = {rw.x, rw.y, rw.z, rw.w};
#pragma unroll
                for (int q = 0; q < 4; ++q) {
                    v[2 * q] = h2f(rr[q]);
                    v[2 * q + 1] = h2f(rr[q] >> 16);
                }
#pragma unroll
                for (int c = 0; c < 8; ++c) {
                    float val = v[c] * bnsc[kq + c] + bnsc[64 + kq + c];
                    v[c] = val >= 0.f ? val : 0.01f * val;
                }
            }
        } else {
#pragma unroll
            for (int c = 0; c < 8; ++c) v[c] = 0.f;
        }
        unsigned short* ap = (unsigned short*)&afrag[ks];
#pragma unroll
        for (int c = 0; c < 8; ++c) ap[c] = f2bf(v[c]);
    }
    __syncthreads();

    f32x4 acc[8];
    f32x4 acc8 = (f32x4)(0.f);
#pragma unroll
    for (int c = 0; c < 8; ++c) acc[c] = (f32x4)(0.f);
#pragma unroll
    for (int ks = 0; ks < K / 32; ++ks) {
        s16x8 a = afrag[ks];
        int k0 = ks * 32;
#pragma unroll
        for (int ct = 0; ct < 8; ++ct) {
            s16x8 b = *(const s16x8*)&Bs[(ct * 16 + lr) * KP + k0 + quad * 8];
            acc[ct] = __builtin_amdgcn_mfma_f32_16x16x32_bf16(a, b, acc[ct], 0, 0, 0);
        }
        s16x8 b9 = *(const s16x8*)&Bs[(128 + (lr & 3)) * KP + k0 + quad * 8];
        acc8 = __builtin_amdgcn_mfma_f32_16x16x32_bf16(a, b9, acc8, 0, 0, 0);
    }

    bool hblock = (!L0) || (tile == 0);
#pragma unroll
    for (int reg = 0; reg < 4; ++reg) {
        int row = rbase + wv * 16 + quad * 4 + reg;
        if (hblock) {
            if (row < NN) {
#pragma unroll
                for (int ct = 0; ct < 4; ++ct) {
                    int pk = __builtin_amdgcn_cvt_pk_fp8_f32(acc[ct][reg], acc[ct + 4][reg],
                                                             0, false);
                    int pn = __shfl_xor(pk, 1, 64);  // partner channel (lr^1)
                    if (!(lr & 1))
                        Hq32[(size_t)row * 32 + ct * 8 + (lr >> 1)] =
                            (unsigned int)((pk & 0xFFFF) | (pn << 16));
                }
            }
            // scores: lane lr holds col 128+(lr&3): 0=s_h0 1=s_h1 2=d_h0 3=d_h1
            float own = acc8[reg];
            float par = __shfl_xor(own, 1, 64);
            if (row < NN) {
                unsigned int pkv = (unsigned)f2bf(own) | ((unsigned)f2bf(par) << 16);
                if (lr == 0) e_srcpk[row] = pkv;
                else if (lr == 2) e_dstpk[row] = pkv;
            }
        } else if (row < NN) {
#pragma unroll
            for (int ct = 0; ct < 4; ++ct)
                skipx[(size_t)row * 64 + ct * 16 + lr] = (_Float16)acc[ct][reg];
#pragma unroll
            for (int ct = 4; ct < 8; ++ct) {
                int c = (ct - 4) * 16 + lr;
                jkproj[(size_t)row * 64 + c] = (_Float16)(acc[ct][reg] + projb[c]);
            }
        }
    }
}

// Per-edge records in CSR order: erec[i] = {src, packed bf16x2 weight}.
// Thread-per-edge: each exp computed exactly once (vs 64x redundant if fused
// into the per-node aggregate wave -- measured +29% VALUBusy regression).
__global__ void edge_w(const int* __restrict__ csr_src, const int* __restrict__ csr_dst,
                       const unsigned int* __restrict__ e_srcpk,
                       const unsigned int* __restrict__ e_dstpk,
                       uint2* __restrict__ erec) {
    int i = blockIdx.x * blockDim.x + threadIdx.x;
    if (i >= NE) return;
    int s = csr_src[i];
    unsigned int q = e_srcpk[s];
    unsigned int r = e_dstpk[csr_dst[i]];
    float a0 = bf_lo(q) + bf_lo(r);
    float a1 = bf_hi(q) + bf_hi(r);
    a0 = a0 >= 0.f ? a0 : 0.2f * a0;
    a1 = a1 >= 0.f ? a1 : 0.2f * a1;
    unsigned int w = (unsigned int)f2bf(__expf(a0)) | ((unsigned int)f2bf(__expf(a1)) << 16);
    erec[i] = make_uint2((unsigned)s, w);
}

// One wave per destination node, lane = channel (0..63). Per edge: one
// wave-uniform erec load (src + precomputed weight, readfirstlane -> SGPR),
// one per-lane ushort fp8 gather (one 128B line/edge), ~8 lean VALU ops.
// Three-phase batching (issue all erec loads -> all gathers -> consume);
// M=16 top tier keeps ~16 gathers in flight (avg degree = 16).
// NOTE: best-measured structure (47.3us). Chunked (16 nodes/wave) and 3-deep
// explicit pipelining both regressed (+5% / +60%) -- per-edge boundary checks
// and lost occupancy cost more than the latency they hide.
__global__ __launch_bounds__(256) void aggregate(
    const int* __restrict__ offsets, const uint2* __restrict__ erec,
    const unsigned int* __restrict__ Hq32, const _Float16* __restrict__ skipsrc,
    const float* __restrict__ bnsc, const float* __restrict__ bias,
    _Float16* __restrict__ hraw) {
    int wave = threadIdx.x >> 6;
    int lane = threadIdx.x & 63;
    int n = blockIdx.x * 4 + wave;
    if (n >= NN) return;
    const unsigned char* __restrict__ Hq8 = (const unsigned char*)Hq32;
    int beg = __builtin_amdgcn_readfirstlane(offsets[n]);
    int end = __builtin_amdgcn_readfirstlane(offsets[n + 1]);
    int voff = lane * 2;  // byte offset of this lane's (head0,head1) fp8 pair

    float sv = (float)skipsrc[(size_t)n * 64 + lane];  // issued early
    float bi = bias[lane];
    float bsc = 0.f, bsh = 0.f;
    if (bnsc) {
        bsc = bnsc[lane];
        bsh = bnsc[64 + lane];
    }

    float a0 = 0.f, a1 = 0.f, den0 = 0.f, den1 = 0.f;
    int j = beg;

    auto batch = [&](auto Mc) {
        constexpr int M = decltype(Mc)::value;
        uint2 ee[M];
#pragma unroll
        for (int u = 0; u < M; ++u) ee[u] = erec[j + u];
        int ss[M];
        unsigned ww[M];
#pragma unroll
        for (int u = 0; u < M; ++u) {
            ss[u] = __builtin_amdgcn_readfirstlane((int)ee[u].x);
            ww[u] = (unsigned)__builtin_amdgcn_readfirstlane((int)ee[u].y);
        }
        unsigned short uu[M];
#pragma unroll
        for (int u = 0; u < M; ++u)
            uu[u] = *(const unsigned short*)(Hq8 + (size_t)ss[u] * 128 + voff);
#pragma unroll
        for (int u = 0; u < M; ++u) {
            float w0 = bf_lo(ww[u]), w1 = bf_hi(ww[u]);
            f32x2 hv = __builtin_amdgcn_cvt_pk_f32_fp8((int)uu[u], false);
            den0 += w0;
            den1 += w1;
            a0 += w0 * hv[0];
            a1 += w1 * hv[1];
        }
        j += M;
    };

    while (j + 16 <= end) batch(IC<16>{});
    if (j + 8 <= end) batch(IC<8>{});
    if (j + 4 <= end) batch(IC<4>{});
    if (j + 2 <= end) batch(IC<2>{});
    if (j < end) batch(IC<1>{});

    if (bnsc) {  // identity skip from previous layer's pre-BN buffer
        sv = sv * bsc + bsh;
        sv = sv >= 0.f ? sv : 0.01f * sv;
    }
    float id0 = 1.f / (den0 + 1e-16f), id1 = 1.f / (den1 + 1e-16f);
    float o = 0.5f * (a0 * id0 + a1 * id1) + bi + sv;
    hraw[(size_t)n * 64 + lane] = (_Float16)o;
}

// BN stats, rebuilt for occupancy: grid-stride 1024 blocks (was 196 -- 7%
// occupancy, 50us latency-bound). Each thread: one uint4 load = 8 fp16
// channels (wave covers 8 rows x 64ch = 1KB contiguous per iter), 8 (s,s2)
// register accumulators, ~3 iterations. LDS-atomic block reduce, one global
// atomic per channel per block. FUSED finalize in the last block (ticket).
__global__ __launch_bounds__(256) void bn_stats(const _Float16* __restrict__ x,
                                                float* __restrict__ sums,
                                                const float* __restrict__ g,
                                                const float* __restrict__ be,
                                                float* __restrict__ sc_sh,
                                                int* __restrict__ ticket) {
    __shared__ float lsum[64], lsum2[64];
    __shared__ int isLast;
    int t = threadIdx.x;
    int c8 = t & 7, q = t >> 3;  // channel-octet, row-slot (0..31)
    int cbase = c8 * 8;
    float s[8], s2[8];
#pragma unroll
    for (int k = 0; k < 8; ++k) s[k] = s2[k] = 0.f;
    for (int r = blockIdx.x * 32 + q; r < NN; r += BN_BLOCKS * 32) {
        uint4 v = *(const uint4*)&x[(size_t)r * 64 + cbase];
        unsigned rr[4] = {v.x, v.y, v.z, v.w};
#pragma unroll
        for (int k = 0; k < 4; ++k) {
            float f0 = h2f(rr[k]);
            float f1 = h2f(rr[k] >> 16);
            s[2 * k] += f0;
            s2[2 * k] += f0 * f0;
            s[2 * k + 1] += f1;
            s2[2 * k + 1] += f1 * f1;
        }
    }
    if (t < 64) {
        lsum[t] = 0.f;
        lsum2[t] = 0.f;
    }
    __syncthreads();
#pragma unroll
    for (int k = 0; k < 8; ++k) {
        atomicAdd(&lsum[cbase + k], s[k]);
        atomicAdd(&lsum2[cbase + k], s2[k]);
    }
    __syncthreads();
    if (t < 64) {
        atomicAdd(&sums[t], lsum[t]);
        atomicAdd(&sums[64 + t], lsum2[t]);
    }
    __threadfence();
    if (t == 0) isLast = (atomicAdd(ticket, 1) == BN_BLOCKS - 1);
    __syncthreads();
    if (isLast && t < 64) {
        float fs = atomicAdd(&sums[t], 0.f);
        float fs2 = atomicAdd(&sums[64 + t], 0.f);
        float mu = fs / (float)NN;
        float var = fs2 / (float)NN - mu * mu;
        float sc = g[t] * rsqrtf(var + 1e-5f);
        sc_sh[t] = sc;
        sc_sh[64 + t] = be[t] - mu * sc;
    }
}

// JK max over {input proj, lrelu(bn_k(hraw_k))} for k=0,1,2 in one pass.
__global__ void final_out(const _Float16* __restrict__ jkproj, const _Float16* __restrict__ hA,
                          const _Float16* __restrict__ hB, const _Float16* __restrict__ hC,
                          const float* __restrict__ bnAll, float* __restrict__ out) {
    int i = blockIdx.x * blockDim.x + threadIdx.x;
    if (i < NN * 64) {
        int c = i & 63;
        float v0 = (float)hA[i] * bnAll[c] + bnAll[64 + c];
        float v1 = (float)hB[i] * bnAll[128 + c] + bnAll[192 + c];
        float v2 = (float)hC[i] * bnAll[256 + c] + bnAll[320 + c];
        v0 = v0 >= 0.f ? v0 : 0.01f * v0;
        v1 = v1 >= 0.f ? v1 : 0.01f * v1;
        v2 = v2 >= 0.f ? v2 : 0.01f * v2;
        out[i] = fmaxf(fmaxf((float)jkproj[i], v0), fmaxf(v1, v2));
    }
}

extern "C" void kernel_launch(void* const* d_in, const int* in_sizes, int n_in,
                              void* d_out, int out_size, void* d_ws, size_t ws_size,
                              hipStream_t stream) {
    const float* x = (const float*)d_in[0];
    const int* ei = (const int*)d_in[1];
    const int* e_src_idx = ei;
    const int* e_dst_idx = ei + NE;
    const float* W0 = (const float*)d_in[2];
    const float* as0 = (const float*)d_in[3];
    const float* ad0 = (const float*)d_in[4];
    const float* b0 = (const float*)d_in[5];
    const float* skip0 = (const float*)d_in[6];
    const float* g0 = (const float*)d_in[7];
    const float* be0 = (const float*)d_in[8];
    const float* W1 = (const float*)d_in[9];
    const float* as1 = (const float*)d_in[10];
    const float* ad1 = (const float*)d_in[11];
    const float* b1 = (const float*)d_in[12];
    const float* g1 = (const float*)d_in[13];
    const float* be1 = (const float*)d_in[14];
    const float* W2 = (const float*)d_in[15];
    const float* as2 = (const float*)d_in[16];
    const float* ad2 = (const float*)d_in[17];
    const float* b2 = (const float*)d_in[18];
    const float* g2 = (const float*)d_in[19];
    const float* be2 = (const float*)d_in[20];
    const float* projW = (const float*)d_in[21];
    const float* projb = (const float*)d_in[22];
    float* out = (float*)d_out;

    char* p = (char*)d_ws;
    auto alloc = [&](size_t bytes) {
        char* r = p;
        p += (bytes + 255) & ~(size_t)255;
        return r;
    };
    // bcount (196) + bnsumAll (384) + tickets (3) share one zeroed buffer.
    int* zbuf = (int*)alloc((size_t)(196 + 384 + 3) * 4);
    int* bcount = zbuf;
    float* bnsumAll = (float*)(zbuf + 196);
    int* tickets = zbuf + 196 + 384;
    int* bbase = (int*)alloc((size_t)(NBUC + 1) * 4);
    int* bucket_cursor = (int*)alloc((size_t)NBUC * 4);
    int* offsets = (int*)alloc((size_t)(NN + 1) * 4);
    int* csr_src = (int*)alloc((size_t)NE * 4);
    int* csr_dst = (int*)alloc((size_t)NE * 4);
    uint2* erec = (uint2*)alloc((size_t)NE * 8);
    unsigned int* binned = (unsigned int*)alloc((size_t)NE * 4);
    unsigned int* h_q32 = (unsigned int*)alloc((size_t)NN * 32 * 4);
    unsigned int* e_srcpk = (unsigned int*)alloc((size_t)NN * 4);
    unsigned int* e_dstpk = (unsigned int*)alloc((size_t)NN * 4);
    _Float16* skipx = (_Float16*)alloc((size_t)NN * 64 * 2);
    _Float16* jkproj = (_Float16*)alloc((size_t)NN * 64 * 2);
    _Float16* hrawA = (_Float16*)alloc((size_t)NN * 64 * 2);
    _Float16* hrawB = (_Float16*)alloc((size_t)NN * 64 * 2);
    _Float16* hrawC = (_Float16*)alloc((size_t)NN * 64 * 2);
    unsigned short* Wtcat = (unsigned short*)alloc((size_t)2 * 132 * 128 * 2);
    unsigned short* Wt1 = (unsigned short*)alloc((size_t)132 * 64 * 2);
    unsigned short* Wt2 = (unsigned short*)alloc((size_t)132 * 64 * 2);
    float* bnscAll = (float*)alloc(3 * 128 * 4);
    if ((size_t)(p - (char*)d_ws) > ws_size) return;

    // ---- CSR by destination: bucket count -> scan -> bin -> LDS sort ----
    zero_u32<<<3, 256, 0, stream>>>((unsigned int*)zbuf, 196 + 384 + 3);
    bucket_count<<<NB_BIN, 256, 0, stream>>>(e_dst_idx, bcount);
    bucket_scan<<<1, 64, 0, stream>>>(bcount, bbase, bucket_cursor, offsets);
    bin_edges<<<NB_BIN, 256, 0, stream>>>(e_src_idx, e_dst_idx, bucket_cursor, binned);
    bucket_sort<<<NBUC, 256, 0, stream>>>(binned, bbase, offsets, csr_src, csr_dst);
    prep_weights<<<198, 256, 0, stream>>>(W0, skip0, projW, W1, W2, as0, ad0, as1, ad1,
                                          as2, ad2, Wtcat, Wt1, Wt2);

    int gblocks = (NN + 63) / 64;  // 1563
    int ablocks = (NN + 3) / 4;    // 25000

    // ---- Layer 0 (one GEMM: h+scores | skip+proj; y = row blocks) ----
    gemm_mfma<128, true, false><<<dim3(2, gblocks), 256, 0, stream>>>(
        x, Wtcat, h_q32, skipx, jkproj, projb, nullptr, e_srcpk, e_dstpk);
    edge_w<<<(NE + 255) / 256, 256, 0, stream>>>(csr_src, csr_dst, e_srcpk, e_dstpk, erec);
    aggregate<<<ablocks, 256, 0, stream>>>(offsets, erec, h_q32, skipx, nullptr, b0,
                                           hrawA);
    bn_stats<<<BN_BLOCKS, 256, 0, stream>>>(hrawA, bnsumAll, g0, be0, bnscAll, tickets);

    // ---- Layer 1 ----
    gemm_mfma<64, false, true><<<dim3(gblocks, 1), 256, 0, stream>>>(
        hrawA, Wt1, h_q32, nullptr, nullptr, nullptr, bnscAll, e_srcpk, e_dstpk);
    edge_w<<<(NE + 255) / 256, 256, 0, stream>>>(csr_src, csr_dst, e_srcpk, e_dstpk, erec);
    aggregate<<<ablocks, 256, 0, stream>>>(offsets, erec, h_q32, hrawA, bnscAll, b1,
                                           hrawB);
    bn_stats<<<BN_BLOCKS, 256, 0, stream>>>(hrawB, bnsumAll + 128, g1, be1, bnscAll + 128,
                                            tickets + 1);

    // ---- Layer 2 ----
    gemm_mfma<64, false, true><<<dim3(gblocks, 1), 256, 0, stream>>>(
        hrawB, Wt2, h_q32, nullptr, nullptr, nullptr, bnscAll + 128, e_srcpk, e_dstpk);
    edge_w<<<(NE + 255) / 256, 256, 0, stream>>>(csr_src, csr_dst, e_srcpk, e_dstpk, erec);
    aggregate<<<ablocks, 256, 0, stream>>>(offsets, erec, h_q32, hrawB, bnscAll + 128,
                                           b2, hrawC);
    bn_stats<<<BN_BLOCKS, 256, 0, stream>>>(hrawC, bnsumAll + 256, g2, be2, bnscAll + 256,
                                            tickets + 2);

    final_out<<<(NN * 64 + 255) / 256, 256, 0, stream>>>(jkproj, hrawA, hrawB, hrawC,
                                                         bnscAll, out);
}

// Round 11
// 490.962 us; speedup vs baseline: 1.2819x; 1.2819x over previous
//
#include <hip/hip_runtime.h>

#define NN 100000
#define NE 1600000

constexpr int NBUC = 196;       // bucket = dst >> 9 (512 nodes/bucket)
constexpr int BIN_CHUNK = 4096;
constexpr int NB_BIN = (NE + BIN_CHUNK - 1) / BIN_CHUNK;  // 391
constexpr int NPART = 512;      // bn_stats blocks (partials, no atomics)

typedef __attribute__((ext_vector_type(8))) short s16x8;
typedef __attribute__((ext_vector_type(4))) float f32x4;
typedef __attribute__((ext_vector_type(2))) float f32x2;

template <int M>
struct IC {
    static constexpr int value = M;
};

__device__ inline unsigned short f2bf(float f) {  // RNE fp32 -> bf16 bits
    unsigned int u = __float_as_uint(f);
    return (unsigned short)((u + 0x7fffu + ((u >> 16) & 1u)) >> 16);
}
__device__ inline float bf_lo(unsigned int pk) { return __uint_as_float(pk << 16); }
__device__ inline float bf_hi(unsigned int pk) { return __uint_as_float(pk & 0xffff0000u); }
__device__ inline float h2f(unsigned int u) {  // low 16 bits = fp16
    _Float16 h;
    unsigned short s = (unsigned short)u;
    __builtin_memcpy(&h, &s, 2);
    return (float)h;
}

__global__ void zero_u32(unsigned int* p, int n) {
    int i = blockIdx.x * blockDim.x + threadIdx.x;
    if (i < n) p[i] = 0u;
}

// Histogram of dst buckets (LDS-combined, 196 global atomics per block).
__global__ __launch_bounds__(256) void bucket_count(const int* __restrict__ dst,
                                                    int* __restrict__ bcount) {
    __shared__ int hist[NBUC];
    int t = threadIdx.x;
    for (int b = t; b < NBUC; b += 256) hist[b] = 0;
    __syncthreads();
    int beg = blockIdx.x * BIN_CHUNK;
    int end = min(beg + BIN_CHUNK, NE);
    for (int i = beg + t; i < end; i += 256) atomicAdd(&hist[dst[i] >> 9], 1);
    __syncthreads();
    for (int b = t; b < NBUC; b += 256)
        if (hist[b]) atomicAdd(&bcount[b], hist[b]);
}

// Serial 196-entry exclusive scan; writes bucket bases + bin cursors.
__global__ void bucket_scan(const int* __restrict__ bcount, int* __restrict__ bbase,
                            int* __restrict__ bucket_cursor, int* __restrict__ offsets) {
    if (threadIdx.x == 0) {
        int run = 0;
        for (int b = 0; b < NBUC; ++b) {
            bbase[b] = run;
            bucket_cursor[b] = run;
            run += bcount[b];
        }
        bbase[NBUC] = NE;
        offsets[NN] = NE;
    }
}

// Bucket-major packed intermediate: (local_dst9 << 17) | src17. Per-block LDS
// histogram, per-bucket chunk reservation, contiguous 4B writes.
__global__ __launch_bounds__(256) void bin_edges(const int* __restrict__ src,
                                                 const int* __restrict__ dst,
                                                 int* __restrict__ bucket_cursor,
                                                 unsigned int* __restrict__ binned) {
    __shared__ int hist[NBUC];
    __shared__ int base[NBUC];
    int t = threadIdx.x;
    for (int b = t; b < NBUC; b += 256) hist[b] = 0;
    __syncthreads();
    int beg = blockIdx.x * BIN_CHUNK;
    int end = min(beg + BIN_CHUNK, NE);
    for (int i = beg + t; i < end; i += 256) atomicAdd(&hist[dst[i] >> 9], 1);
    __syncthreads();
    for (int b = t; b < NBUC; b += 256) {
        base[b] = hist[b] ? atomicAdd(&bucket_cursor[b], hist[b]) : 0;
        hist[b] = 0;
    }
    __syncthreads();
    for (int i = beg + t; i < end; i += 256) {
        int d = dst[i];
        int bk = d >> 9;
        int loc = atomicAdd(&hist[bk], 1);
        binned[base[bk] + loc] = ((unsigned)(d & 511) << 17) | (unsigned)src[i];
    }
}

// One block per bucket: LDS counting sort over the bucket's 512 nodes.
// Emits offsets + csr_src/csr_dst with sequential (in-bucket) global writes.
__global__ __launch_bounds__(256) void bucket_sort(const unsigned int* __restrict__ binned,
                                                   const int* __restrict__ bbase,
                                                   int* __restrict__ offsets,
                                                   int* __restrict__ csr_src,
                                                   int* __restrict__ csr_dst) {
    __shared__ int deg[512];
    __shared__ int loc[512];
    __shared__ int s2[256];
    int t = threadIdx.x;
    int b = blockIdx.x;
    int beg = bbase[b], end = bbase[b + 1];
    int nbase = b << 9;
    deg[t] = 0;
    deg[t + 256] = 0;
    __syncthreads();
    for (int i = beg + t; i < end; i += 256) atomicAdd(&deg[binned[i] >> 17], 1);
    __syncthreads();
    int pairsum = deg[2 * t] + deg[2 * t + 1];
    s2[t] = pairsum;
    __syncthreads();
    for (int off = 1; off < 256; off <<= 1) {
        int v = (t >= off) ? s2[t - off] : 0;
        __syncthreads();
        s2[t] += v;
        __syncthreads();
    }
    int ex = s2[t] - pairsum;  // exclusive pair base
    loc[2 * t] = ex;
    loc[2 * t + 1] = ex + deg[2 * t];
    __syncthreads();
    for (int i = t; i < 512; i += 256) {
        int node = nbase + i;
        if (node < NN) offsets[node] = beg + loc[i];
    }
    __syncthreads();
    for (int i = beg + t; i < end; i += 256) {
        unsigned int v = binned[i];
        int dl = v >> 17;
        int pos = atomicAdd(&loc[dl], 1);
        csr_src[beg + pos] = (int)(v & 0x1FFFFu);
        csr_dst[beg + pos] = nbase + dl;
    }
}

// Transpose + fp32->bf16 all weights once per launch, and FOLD the attention
// score vectors into the GEMM B matrix: scores are linear in X, so
// e_src[n,h] = X @ (W[:,h*64:]*as[h]) -> 4 extra B columns (128..131) per
// tile: [was_h0, was_h1, wad_h0, wad_h1].
// Wtcat: 2 tiles x 132 cols x 128 k. tile0 = W0(h)+scores; tile1 = skip|proj.
// Wt1/Wt2: 132 cols x 64 k.
__global__ void prep_weights(const float* __restrict__ W0, const float* __restrict__ skip0,
                             const float* __restrict__ projW, const float* __restrict__ W1,
                             const float* __restrict__ W2,
                             const float* __restrict__ as0, const float* __restrict__ ad0,
                             const float* __restrict__ as1, const float* __restrict__ ad1,
                             const float* __restrict__ as2, const float* __restrict__ ad2,
                             unsigned short* __restrict__ Wtcat,
                             unsigned short* __restrict__ Wt1,
                             unsigned short* __restrict__ Wt2) {
    int i = blockIdx.x * 256 + threadIdx.x;
    if (i < 16384) {  // Wtcat tile0 h cols
        int oc = i >> 7, k = i & 127;
        Wtcat[oc * 128 + k] = f2bf(W0[k * 128 + oc]);
    } else if (i < 32768) {  // Wtcat tile1: skip | proj
        int j = i - 16384;
        int oc = j >> 7, k = j & 127;
        float v = (oc < 64) ? skip0[k * 64 + oc] : projW[k * 64 + (oc - 64)];
        Wtcat[132 * 128 + oc * 128 + k] = f2bf(v);
    } else if (i < 40960) {  // Wt1 h cols
        int j = i - 32768, oc = j >> 6, k = j & 63;
        Wt1[oc * 64 + k] = f2bf(W1[k * 128 + oc]);
    } else if (i < 49152) {  // Wt2 h cols
        int j = i - 40960, oc = j >> 6, k = j & 63;
        Wt2[oc * 64 + k] = f2bf(W2[k * 128 + oc]);
    } else if (i < 50688) {  // score columns
        int e = i - 49152;
        if (e < 512) {  // Wtcat tile0 scores: 4 cols x 128 k
            int k = e >> 2, sc = e & 3, head = sc & 1;
            const float* av = (sc < 2 ? as0 : ad0) + head * 64;
            const float* wr = W0 + k * 128 + head * 64;
            float s = 0.f;
            for (int c = 0; c < 64; ++c) s += wr[c] * av[c];
            Wtcat[(128 + sc) * 128 + k] = f2bf(s);
        } else if (e < 1024) {  // tile1 score cols = 0 (unused)
            int j = e - 512, k = j >> 2, sc = j & 3;
            Wtcat[132 * 128 + (128 + sc) * 128 + k] = 0;
        } else if (e < 1280) {
            int j = e - 1024, k = j >> 2, sc = j & 3, head = sc & 1;
            const float* av = (sc < 2 ? as1 : ad1) + head * 64;
            const float* wr = W1 + k * 128 + head * 64;
            float s = 0.f;
            for (int c = 0; c < 64; ++c) s += wr[c] * av[c];
            Wt1[(128 + sc) * 64 + k] = f2bf(s);
        } else {
            int j = e - 1280, k = j >> 2, sc = j & 3, head = sc & 1;
            const float* av = (sc < 2 ? as2 : ad2) + head * 64;
            const float* wr = W2 + k * 128 + head * 64;
            float s = 0.f;
            for (int c = 0; c < 64; ++c) s += wr[c] * av[c];
            Wt2[(128 + sc) * 64 + k] = f2bf(s);
        }
    }
}

// MFMA bf16 GEMM: block = 64 rows x 132 cols (128 data + 4 score), 4 waves.
// A-side: NO LDS staging -- each lane loads its MFMA fragment slice directly
// from global (fp32 x for L0, fp16 hraw+BN+lrelu for L1/L2), converts to bf16
// in registers, and reuses it across all 9 column tiles. Only B lives in LDS
// (35.9KB for K=128 -> 4 blocks/CU vs 2 with A staged; 19KB for K=64).
// h written as [node][32] dwords of packed fp8-e4m3 (head0,head1) pairs.
// Scores via a 9th MFMA against cols 128+(lr&3) -> 1-shfl epilogue.
template <int K, bool L0, bool XFORM>
__global__ __launch_bounds__(256, 4) void gemm_mfma(
    const void* __restrict__ Xv, const unsigned short* __restrict__ Wt,
    unsigned int* __restrict__ Hq32, _Float16* __restrict__ skipx,
    _Float16* __restrict__ jkproj, const float* __restrict__ projb,
    const float* __restrict__ bnsc,
    unsigned int* __restrict__ e_srcpk, unsigned int* __restrict__ e_dstpk) {
    constexpr int KP = K + 8;
    constexpr int NC = 132;
    __shared__ unsigned short Bs[NC * KP];
    int t = threadIdx.x;
    int tile = L0 ? blockIdx.x : 0;
    int rbase = (L0 ? blockIdx.y : blockIdx.x) * 64;
    const unsigned short* Wtg = Wt + (size_t)tile * NC * K;

    for (int i = t; i < NC * (K / 8); i += 256) {
        int oc = i / (K / 8);
        int k8 = (i % (K / 8)) * 8;
        uint4 v = *(const uint4*)&Wtg[(size_t)oc * K + k8];
        *(uint4*)&Bs[oc * KP + k8] = v;
    }

    int lane = t & 63, wv = t >> 6;
    int lr = lane & 15, quad = lane >> 4;
    int arow = wv * 16 + lr;
    int grow = rbase + arow;
    bool rowok = grow < NN;

    // A fragments: K/32 x s16x8, loaded global->reg with inline bf16 convert.
    s16x8 afrag[K / 32];
#pragma unroll
    for (int ks = 0; ks < K / 32; ++ks) {
        int kq = ks * 32 + quad * 8;
        float v[8];
        if (rowok) {
            if constexpr (!XFORM) {
                const float* Xf = (const float*)Xv;
                float4 p0 = *(const float4*)&Xf[(size_t)grow * K + kq];
                float4 p1 = *(const float4*)&Xf[(size_t)grow * K + kq + 4];
                v[0] = p0.x; v[1] = p0.y; v[2] = p0.z; v[3] = p0.w;
                v[4] = p1.x; v[5] = p1.y; v[6] = p1.z; v[7] = p1.w;
            } else {
                const _Float16* Xh = (const _Float16*)Xv;
                uint4 rw = *(const uint4*)&Xh[(size_t)grow * K + kq];
                unsigned rr[4] = {rw.x, rw.y, rw.z, rw.w};
#pragma unroll
                for (int q = 0; q < 4; ++q) {
                    v[2 * q] = h2f(rr[q]);
                    v[2 * q + 1] = h2f(rr[q] >> 16);
                }
#pragma unroll
                for (int c = 0; c < 8; ++c) {
                    float val = v[c] * bnsc[kq + c] + bnsc[64 + kq + c];
                    v[c] = val >= 0.f ? val : 0.01f * val;
                }
            }
        } else {
#pragma unroll
            for (int c = 0; c < 8; ++c) v[c] = 0.f;
        }
        unsigned short* ap = (unsigned short*)&afrag[ks];
#pragma unroll
        for (int c = 0; c < 8; ++c) ap[c] = f2bf(v[c]);
    }
    __syncthreads();

    f32x4 acc[8];
    f32x4 acc8 = (f32x4)(0.f);
#pragma unroll
    for (int c = 0; c < 8; ++c) acc[c] = (f32x4)(0.f);
#pragma unroll
    for (int ks = 0; ks < K / 32; ++ks) {
        s16x8 a = afrag[ks];
        int k0 = ks * 32;
#pragma unroll
        for (int ct = 0; ct < 8; ++ct) {
            s16x8 b = *(const s16x8*)&Bs[(ct * 16 + lr) * KP + k0 + quad * 8];
            acc[ct] = __builtin_amdgcn_mfma_f32_16x16x32_bf16(a, b, acc[ct], 0, 0, 0);
        }
        s16x8 b9 = *(const s16x8*)&Bs[(128 + (lr & 3)) * KP + k0 + quad * 8];
        acc8 = __builtin_amdgcn_mfma_f32_16x16x32_bf16(a, b9, acc8, 0, 0, 0);
    }

    bool hblock = (!L0) || (tile == 0);
#pragma unroll
    for (int reg = 0; reg < 4; ++reg) {
        int row = rbase + wv * 16 + quad * 4 + reg;
        if (hblock) {
            if (row < NN) {
#pragma unroll
                for (int ct = 0; ct < 4; ++ct) {
                    int pk = __builtin_amdgcn_cvt_pk_fp8_f32(acc[ct][reg], acc[ct + 4][reg],
                                                             0, false);
                    int pn = __shfl_xor(pk, 1, 64);  // partner channel (lr^1)
                    if (!(lr & 1))
                        Hq32[(size_t)row * 32 + ct * 8 + (lr >> 1)] =
                            (unsigned int)((pk & 0xFFFF) | (pn << 16));
                }
            }
            // scores: lane lr holds col 128+(lr&3): 0=s_h0 1=s_h1 2=d_h0 3=d_h1
            float own = acc8[reg];
            float par = __shfl_xor(own, 1, 64);
            if (row < NN) {
                unsigned int pkv = (unsigned)f2bf(own) | ((unsigned)f2bf(par) << 16);
                if (lr == 0) e_srcpk[row] = pkv;
                else if (lr == 2) e_dstpk[row] = pkv;
            }
        } else if (row < NN) {
#pragma unroll
            for (int ct = 0; ct < 4; ++ct)
                skipx[(size_t)row * 64 + ct * 16 + lr] = (_Float16)acc[ct][reg];
#pragma unroll
            for (int ct = 4; ct < 8; ++ct) {
                int c = (ct - 4) * 16 + lr;
                jkproj[(size_t)row * 64 + c] = (_Float16)(acc[ct][reg] + projb[c]);
            }
        }
    }
}

// Per-edge records in CSR order: erec[i] = {src, packed bf16x2 weight}.
// Thread-per-edge: each exp computed exactly once (vs 64x redundant if fused
// into the per-node aggregate wave -- measured +29% VALUBusy regression).
__global__ void edge_w(const int* __restrict__ csr_src, const int* __restrict__ csr_dst,
                       const unsigned int* __restrict__ e_srcpk,
                       const unsigned int* __restrict__ e_dstpk,
                       uint2* __restrict__ erec) {
    int i = blockIdx.x * blockDim.x + threadIdx.x;
    if (i >= NE) return;
    int s = csr_src[i];
    unsigned int q = e_srcpk[s];
    unsigned int r = e_dstpk[csr_dst[i]];
    float a0 = bf_lo(q) + bf_lo(r);
    float a1 = bf_hi(q) + bf_hi(r);
    a0 = a0 >= 0.f ? a0 : 0.2f * a0;
    a1 = a1 >= 0.f ? a1 : 0.2f * a1;
    unsigned int w = (unsigned int)f2bf(__expf(a0)) | ((unsigned int)f2bf(__expf(a1)) << 16);
    erec[i] = make_uint2((unsigned)s, w);
}

// One wave per destination node, lane = channel (0..63). Per edge: one
// wave-uniform erec load (src + precomputed weight, readfirstlane -> SGPR),
// one per-lane ushort fp8 gather (one 128B line/edge), ~8 lean VALU ops.
// Three-phase batching (issue all erec loads -> all gathers -> consume);
// M=16 top tier keeps ~16 gathers in flight (avg degree = 16).
// NOTE: best-measured structure (47.3us). Chunked (16 nodes/wave) and 3-deep
// explicit pipelining both regressed (+5% / +60%) -- per-edge boundary checks
// and lost occupancy cost more than the latency they hide.
__global__ __launch_bounds__(256) void aggregate(
    const int* __restrict__ offsets, const uint2* __restrict__ erec,
    const unsigned int* __restrict__ Hq32, const _Float16* __restrict__ skipsrc,
    const float* __restrict__ bnsc, const float* __restrict__ bias,
    _Float16* __restrict__ hraw) {
    int wave = threadIdx.x >> 6;
    int lane = threadIdx.x & 63;
    int n = blockIdx.x * 4 + wave;
    if (n >= NN) return;
    const unsigned char* __restrict__ Hq8 = (const unsigned char*)Hq32;
    int beg = __builtin_amdgcn_readfirstlane(offsets[n]);
    int end = __builtin_amdgcn_readfirstlane(offsets[n + 1]);
    int voff = lane * 2;  // byte offset of this lane's (head0,head1) fp8 pair

    float sv = (float)skipsrc[(size_t)n * 64 + lane];  // issued early
    float bi = bias[lane];
    float bsc = 0.f, bsh = 0.f;
    if (bnsc) {
        bsc = bnsc[lane];
        bsh = bnsc[64 + lane];
    }

    float a0 = 0.f, a1 = 0.f, den0 = 0.f, den1 = 0.f;
    int j = beg;

    auto batch = [&](auto Mc) {
        constexpr int M = decltype(Mc)::value;
        uint2 ee[M];
#pragma unroll
        for (int u = 0; u < M; ++u) ee[u] = erec[j + u];
        int ss[M];
        unsigned ww[M];
#pragma unroll
        for (int u = 0; u < M; ++u) {
            ss[u] = __builtin_amdgcn_readfirstlane((int)ee[u].x);
            ww[u] = (unsigned)__builtin_amdgcn_readfirstlane((int)ee[u].y);
        }
        unsigned short uu[M];
#pragma unroll
        for (int u = 0; u < M; ++u)
            uu[u] = *(const unsigned short*)(Hq8 + (size_t)ss[u] * 128 + voff);
#pragma unroll
        for (int u = 0; u < M; ++u) {
            float w0 = bf_lo(ww[u]), w1 = bf_hi(ww[u]);
            f32x2 hv = __builtin_amdgcn_cvt_pk_f32_fp8((int)uu[u], false);
            den0 += w0;
            den1 += w1;
            a0 += w0 * hv[0];
            a1 += w1 * hv[1];
        }
        j += M;
    };

    while (j + 16 <= end) batch(IC<16>{});
    if (j + 8 <= end) batch(IC<8>{});
    if (j + 4 <= end) batch(IC<4>{});
    if (j + 2 <= end) batch(IC<2>{});
    if (j < end) batch(IC<1>{});

    if (bnsc) {  // identity skip from previous layer's pre-BN buffer
        sv = sv * bsc + bsh;
        sv = sv >= 0.f ? sv : 0.01f * sv;
    }
    float id0 = 1.f / (den0 + 1e-16f), id1 = 1.f / (den1 + 1e-16f);
    float o = 0.5f * (a0 * id0 + a1 * id1) + bi + sv;
    hraw[(size_t)n * 64 + lane] = (_Float16)o;
}

// BN stats pass 1: 512 blocks, uint4 loads (8 fp16/thread, wave = 8 rows x
// 128B contiguous), register accumulators, LDS reduce, then PLAIN coalesced
// stores of 128 partials per block. NO global atomics, NO fences (the R10
// version's 131K same-line atomicAdds + per-block __threadfence were the
// 50-69us wall: VALUBusy 0.9%, 100GB/s).
__global__ __launch_bounds__(256) void bn_stats(const _Float16* __restrict__ x,
                                                float* __restrict__ part) {
    __shared__ float lsum[64], lsum2[64];
    int t = threadIdx.x;
    int c8 = t & 7, q = t >> 3;  // channel-octet, row-slot (0..31)
    int cbase = c8 * 8;
    float s[8], s2[8];
#pragma unroll
    for (int k = 0; k < 8; ++k) s[k] = s2[k] = 0.f;
    for (int r = blockIdx.x * 32 + q; r < NN; r += NPART * 32) {
        uint4 v = *(const uint4*)&x[(size_t)r * 64 + cbase];
        unsigned rr[4] = {v.x, v.y, v.z, v.w};
#pragma unroll
        for (int k = 0; k < 4; ++k) {
            float f0 = h2f(rr[k]);
            float f1 = h2f(rr[k] >> 16);
            s[2 * k] += f0;
            s2[2 * k] += f0 * f0;
            s[2 * k + 1] += f1;
            s2[2 * k + 1] += f1 * f1;
        }
    }
    if (t < 64) {
        lsum[t] = 0.f;
        lsum2[t] = 0.f;
    }
    __syncthreads();
#pragma unroll
    for (int k = 0; k < 8; ++k) {
        atomicAdd(&lsum[cbase + k], s[k]);
        atomicAdd(&lsum2[cbase + k], s2[k]);
    }
    __syncthreads();
    if (t < 128)
        part[(size_t)blockIdx.x * 128 + t] = (t < 64) ? lsum[t] : lsum2[t - 64];
}

// BN stats pass 2 (separate launch -- kernel boundary gives ordering and
// coherence, no fences): 1 block x 1024 threads, 8 groups of 128 each sum
// 64 partial-blocks (coalesced 512B/iter across threads), LDS tree, then
// scale/shift for the next layer.
__global__ __launch_bounds__(1024) void bn_final(const float* __restrict__ part,
                                                 const float* __restrict__ g,
                                                 const float* __restrict__ be,
                                                 float* __restrict__ sc_sh) {
    __shared__ float tot[8][128];
    int t = threadIdx.x;
    int c = t & 127, gh = t >> 7;  // 0..7
    float s = 0.f;
    for (int b = gh * (NPART / 8); b < (gh + 1) * (NPART / 8); ++b)
        s += part[(size_t)b * 128 + c];
    tot[gh][c] = s;
    __syncthreads();
    if (t < 128) {
        float v = tot[0][t];
#pragma unroll
        for (int k = 1; k < 8; ++k) v += tot[k][t];
        tot[0][t] = v;
    }
    __syncthreads();
    if (t < 64) {
        float mu = tot[0][t] / (float)NN;
        float var = tot[0][64 + t] / (float)NN - mu * mu;
        float sc = g[t] * rsqrtf(var + 1e-5f);
        sc_sh[t] = sc;
        sc_sh[64 + t] = be[t] - mu * sc;
    }
}

// JK max over {input proj, lrelu(bn_k(hraw_k))} for k=0,1,2 in one pass.
__global__ void final_out(const _Float16* __restrict__ jkproj, const _Float16* __restrict__ hA,
                          const _Float16* __restrict__ hB, const _Float16* __restrict__ hC,
                          const float* __restrict__ bnAll, float* __restrict__ out) {
    int i = blockIdx.x * blockDim.x + threadIdx.x;
    if (i < NN * 64) {
        int c = i & 63;
        float v0 = (float)hA[i] * bnAll[c] + bnAll[64 + c];
        float v1 = (float)hB[i] * bnAll[128 + c] + bnAll[192 + c];
        float v2 = (float)hC[i] * bnAll[256 + c] + bnAll[320 + c];
        v0 = v0 >= 0.f ? v0 : 0.01f * v0;
        v1 = v1 >= 0.f ? v1 : 0.01f * v1;
        v2 = v2 >= 0.f ? v2 : 0.01f * v2;
        out[i] = fmaxf(fmaxf((float)jkproj[i], v0), fmaxf(v1, v2));
    }
}

extern "C" void kernel_launch(void* const* d_in, const int* in_sizes, int n_in,
                              void* d_out, int out_size, void* d_ws, size_t ws_size,
                              hipStream_t stream) {
    const float* x = (const float*)d_in[0];
    const int* ei = (const int*)d_in[1];
    const int* e_src_idx = ei;
    const int* e_dst_idx = ei + NE;
    const float* W0 = (const float*)d_in[2];
    const float* as0 = (const float*)d_in[3];
    const float* ad0 = (const float*)d_in[4];
    const float* b0 = (const float*)d_in[5];
    const float* skip0 = (const float*)d_in[6];
    const float* g0 = (const float*)d_in[7];
    const float* be0 = (const float*)d_in[8];
    const float* W1 = (const float*)d_in[9];
    const float* as1 = (const float*)d_in[10];
    const float* ad1 = (const float*)d_in[11];
    const float* b1 = (const float*)d_in[12];
    const float* g1 = (const float*)d_in[13];
    const float* be1 = (const float*)d_in[14];
    const float* W2 = (const float*)d_in[15];
    const float* as2 = (const float*)d_in[16];
    const float* ad2 = (const float*)d_in[17];
    const float* b2 = (const float*)d_in[18];
    const float* g2 = (const float*)d_in[19];
    const float* be2 = (const float*)d_in[20];
    const float* projW = (const float*)d_in[21];
    const float* projb = (const float*)d_in[22];
    float* out = (float*)d_out;

    char* p = (char*)d_ws;
    auto alloc = [&](size_t bytes) {
        char* r = p;
        p += (bytes + 255) & ~(size_t)255;
        return r;
    };
    int* zbuf = (int*)alloc((size_t)196 * 4);  // bcount (zeroed)
    int* bcount = zbuf;
    int* bbase = (int*)alloc((size_t)(NBUC + 1) * 4);
    int* bucket_cursor = (int*)alloc((size_t)NBUC * 4);
    int* offsets = (int*)alloc((size_t)(NN + 1) * 4);
    int* csr_src = (int*)alloc((size_t)NE * 4);
    int* csr_dst = (int*)alloc((size_t)NE * 4);
    uint2* erec = (uint2*)alloc((size_t)NE * 8);
    unsigned int* binned = (unsigned int*)alloc((size_t)NE * 4);
    unsigned int* h_q32 = (unsigned int*)alloc((size_t)NN * 32 * 4);
    unsigned int* e_srcpk = (unsigned int*)alloc((size_t)NN * 4);
    unsigned int* e_dstpk = (unsigned int*)alloc((size_t)NN * 4);
    _Float16* skipx = (_Float16*)alloc((size_t)NN * 64 * 2);
    _Float16* jkproj = (_Float16*)alloc((size_t)NN * 64 * 2);
    _Float16* hrawA = (_Float16*)alloc((size_t)NN * 64 * 2);
    _Float16* hrawB = (_Float16*)alloc((size_t)NN * 64 * 2);
    _Float16* hrawC = (_Float16*)alloc((size_t)NN * 64 * 2);
    unsigned short* Wtcat = (unsigned short*)alloc((size_t)2 * 132 * 128 * 2);
    unsigned short* Wt1 = (unsigned short*)alloc((size_t)132 * 64 * 2);
    unsigned short* Wt2 = (unsigned short*)alloc((size_t)132 * 64 * 2);
    float* bnscAll = (float*)alloc(3 * 128 * 4);
    float* part = (float*)alloc((size_t)NPART * 128 * 4);  // bn partials (reused)
    if ((size_t)(p - (char*)d_ws) > ws_size) return;

    // ---- CSR by destination: bucket count -> scan -> bin -> LDS sort ----
    zero_u32<<<1, 256, 0, stream>>>((unsigned int*)zbuf, 196);
    bucket_count<<<NB_BIN, 256, 0, stream>>>(e_dst_idx, bcount);
    bucket_scan<<<1, 64, 0, stream>>>(bcount, bbase, bucket_cursor, offsets);
    bin_edges<<<NB_BIN, 256, 0, stream>>>(e_src_idx, e_dst_idx, bucket_cursor, binned);
    bucket_sort<<<NBUC, 256, 0, stream>>>(binned, bbase, offsets, csr_src, csr_dst);
    prep_weights<<<198, 256, 0, stream>>>(W0, skip0, projW, W1, W2, as0, ad0, as1, ad1,
                                          as2, ad2, Wtcat, Wt1, Wt2);

    int gblocks = (NN + 63) / 64;  // 1563
    int ablocks = (NN + 3) / 4;    // 25000

    // ---- Layer 0 (one GEMM: h+scores | skip+proj; y = row blocks) ----
    gemm_mfma<128, true, false><<<dim3(2, gblocks), 256, 0, stream>>>(
        x, Wtcat, h_q32, skipx, jkproj, projb, nullptr, e_srcpk, e_dstpk);
    edge_w<<<(NE + 255) / 256, 256, 0, stream>>>(csr_src, csr_dst, e_srcpk, e_dstpk, erec);
    aggregate<<<ablocks, 256, 0, stream>>>(offsets, erec, h_q32, skipx, nullptr, b0,
                                           hrawA);
    bn_stats<<<NPART, 256, 0, stream>>>(hrawA, part);
    bn_final<<<1, 1024, 0, stream>>>(part, g0, be0, bnscAll);

    // ---- Layer 1 ----
    gemm_mfma<64, false, true><<<dim3(gblocks, 1), 256, 0, stream>>>(
        hrawA, Wt1, h_q32, nullptr, nullptr, nullptr, bnscAll, e_srcpk, e_dstpk);
    edge_w<<<(NE + 255) / 256, 256, 0, stream>>>(csr_src, csr_dst, e_srcpk, e_dstpk, erec);
    aggregate<<<ablocks, 256, 0, stream>>>(offsets, erec, h_q32, hrawA, bnscAll, b1,
                                           hrawB);
    bn_stats<<<NPART, 256, 0, stream>>>(hrawB, part);
    bn_final<<<1, 1024, 0, stream>>>(part, g1, be1, bnscAll + 128);

    // ---- Layer 2 ----
    gemm_mfma<64, false, true><<<dim3(gblocks, 1), 256, 0, stream>>>(
        hrawB, Wt2, h_q32, nullptr, nullptr, nullptr, bnscAll + 128, e_srcpk, e_dstpk);
    edge_w<<<(NE + 255) / 256, 256, 0, stream>>>(csr_src, csr_dst, e_srcpk, e_dstpk, erec);
    aggregate<<<ablocks, 256, 0, stream>>>(offsets, erec, h_q32, hrawB, bnscAll + 128,
                                           b2, hrawC);
    bn_stats<<<NPART, 256, 0, stream>>>(hrawC, part);
    bn_final<<<1, 1024, 0, stream>>>(part, g2, be2, bnscAll + 256);

    final_out<<<(NN * 64 + 255) / 256, 256, 0, stream>>>(jkproj, hrawA, hrawB, hrawC,
                                                         bnscAll, out);
}